// Round 9
// baseline (108.069 us; speedup 1.0000x reference)
//
#include <hip/hip_runtime.h>
#include <math.h>

#define B_  32
#define F_  10
#define N_  512
#define E_  8192
#define T_  16384      /* B_*N_ total nodes */
#define EC_ 8704       /* per-batch edges incl self-loops: E_+N_ */
#define HC_ 512
#define C_  256

typedef __attribute__((ext_vector_type(8))) short bf16x8;
typedef __attribute__((ext_vector_type(4))) float f32x4;

__device__ __forceinline__ unsigned short f2bf(float f) {
    unsigned int u = __float_as_uint(f);
    u = (u + 0x7fffu + ((u >> 16) & 1u)) >> 16;
    return (unsigned short)u;
}
__device__ __forceinline__ float bf2f(unsigned short b) {
    return __uint_as_float(((unsigned int)b) << 16);
}
__device__ __forceinline__ float dot4(f32x4 a, f32x4 b) {
    f32x4 m = a * b;
    return m[0] + m[1] + m[2] + m[3];
}
__device__ __forceinline__ unsigned int pack2(unsigned short a, unsigned short b) {
    return (unsigned int)a | ((unsigned int)b << 16);
}
// expand packed 2x bf16 -> 2 floats
__device__ __forceinline__ void bf2x2(unsigned int u, float& f0, float& f1) {
    f0 = __uint_as_float(u << 16);
    f1 = __uint_as_float(u & 0xffff0000u);
}
__device__ __forceinline__ void async_cp16(const void* g, void* l) {
    __builtin_amdgcn_global_load_lds(
        (const __attribute__((address_space(1))) unsigned int*)g,
        (__attribute__((address_space(3))) unsigned int*)l, 16, 0, 0);
}

// batch→XCD swizzle
__device__ __forceinline__ int node_map(int bid, int wid) {
    int x = bid & 7;
    int rest = bid >> 3;          // 0..511
    int batch = x * 4 + (rest >> 7);
    int within = rest & 127;
    return batch * 512 + within * 4 + wid;
}

// ---------------- dispatch 1: gemm1 (blocks 0..4095) + W2 split (4096..4351)
//                  + per-batch CSR (block 4352). prep outputs consumed only
//                  from agg0 onward, so concurrency inside the dispatch is safe.
__global__ __launch_bounds__(256) void gemm1_kernel(
    const float* __restrict__ X, const float* __restrict__ W1,
    const float* __restrict__ a_s, const float* __restrict__ a_d,
    unsigned short* __restrict__ Hs, float* __restrict__ als,
    float* __restrict__ ald, float* __restrict__ als2z,
    float* __restrict__ ald2z,
    const int* __restrict__ eidx, const float* __restrict__ W2,
    int* __restrict__ off0, int* __restrict__ csr0,
    unsigned short* __restrict__ Bhi, unsigned short* __restrict__ Blo) {
    __shared__ int shmem[1200];
    int tid = threadIdx.x;

    if (blockIdx.x >= 4096) {
        int pb = blockIdx.x - 4096;
        if (pb < 256) {
            // W2 transpose + hi/lo bf16 split, 32x32 tile, 256 threads
            float* t = (float*)shmem;              // [32][33]
            int bx = pb & 15, by = pb >> 4;
            int kb = bx * 32, nb = by * 32;
            int tx = tid & 31, ty = tid >> 5;
#pragma unroll
            for (int r = ty; r < 32; r += 8)
                t[r * 33 + tx] = W2[(size_t)(kb + r) * HC_ + nb + tx];
            __syncthreads();
#pragma unroll
            for (int r = ty; r < 32; r += 8) {
                float v = t[tx * 33 + r];
                unsigned short h = f2bf(v);
                Bhi[(size_t)(nb + r) * HC_ + kb + tx] = h;
                Blo[(size_t)(nb + r) * HC_ + kb + tx] = f2bf(v - bf2f(h));
            }
        } else {
            // CSR for the batch-0 graph: 512 nodes, 8704 edges
            int* cnt = shmem;          // [512]
            int* scn = shmem + 512;    // [256] pair sums
            for (int i = tid; i < 512; i += 256) cnt[i] = 0;
            __syncthreads();
            const int* edst = eidx + E_;
            for (int j = tid; j < EC_; j += 256) {
                int d = (j < E_) ? edst[j] : (j - E_);
                atomicAdd(&cnt[d], 1);
            }
            __syncthreads();
            int c0 = cnt[2 * tid], c1 = cnt[2 * tid + 1];
            scn[tid] = c0 + c1;
            __syncthreads();
            for (int d = 1; d < 256; d <<= 1) {
                int add = (tid >= d) ? scn[tid - d] : 0;
                __syncthreads();
                scn[tid] += add;
                __syncthreads();
            }
            int e0 = scn[tid] - (c0 + c1);     // exclusive pair prefix
            off0[2 * tid] = e0;
            off0[2 * tid + 1] = e0 + c0;
            cnt[2 * tid] = e0;                 // cursors
            cnt[2 * tid + 1] = e0 + c0;
            if (tid == 255) off0[512] = EC_;
            __syncthreads();
            for (int j = tid; j < EC_; j += 256) {
                int s, d;
                if (j < E_) { s = eidx[j]; d = edst[j]; }
                else { s = d = j - E_; }
                int pos = atomicAdd(&cnt[d], 1);
                csr0[pos] = s;
            }
        }
        return;
    }

    int lane = tid & 63, wid = tid >> 6;
    int node = node_map(blockIdx.x, wid);
    int col = lane * 8;
    float x[F_];
    const float* xp = X + (size_t)node * F_;
#pragma unroll
    for (int k = 0; k < F_; ++k) x[k] = xp[k];
    f32x4 h0 = {0.f, 0.f, 0.f, 0.f}, h1 = h0;
#pragma unroll
    for (int k = 0; k < F_; ++k) {
        f32x4 w0 = *(const f32x4*)&W1[k * HC_ + col];
        f32x4 w1 = *(const f32x4*)&W1[k * HC_ + col + 4];
        h0 += x[k] * w0;
        h1 += x[k] * w1;
    }
    uint4 uh;
    uh.x = pack2(f2bf(h0[0]), f2bf(h0[1]));
    uh.y = pack2(f2bf(h0[2]), f2bf(h0[3]));
    uh.z = pack2(f2bf(h1[0]), f2bf(h1[1]));
    uh.w = pack2(f2bf(h1[2]), f2bf(h1[3]));
    *(uint4*)&Hs[(size_t)node * HC_ + col] = uh;
    float ps = dot4(h0, *(const f32x4*)&a_s[col]) + dot4(h1, *(const f32x4*)&a_s[col + 4]);
    float pd = dot4(h0, *(const f32x4*)&a_d[col]) + dot4(h1, *(const f32x4*)&a_d[col + 4]);
#pragma unroll
    for (int m = 1; m <= 16; m <<= 1) {
        ps += __shfl_xor(ps, m);
        pd += __shfl_xor(pd, m);
    }
    if (lane == 0)  { als[node * 2 + 0] = ps; ald[node * 2 + 0] = pd; }
    if (lane == 32) { als[node * 2 + 1] = ps; ald[node * 2 + 1] = pd; }
    if (lane == 16) {   // zero layer-2 coeff accumulators (filled by gemm2 atomics)
        *(float2*)&als2z[node * 2] = make_float2(0.f, 0.f);
        *(float2*)&ald2z[node * 2] = make_float2(0.f, 0.f);
    }
}

// ---------------- GAT aggregation: wave per dst, per-batch CSR --------------
// MODE 0: output bf16 x1 (feeds MFMA gemm2). MODE 1: fused FC+BN+ReLU.
template <int MODE>
__global__ __launch_bounds__(256) void agg_kernel(
    const unsigned short* __restrict__ Hin, const float* __restrict__ als,
    const float* __restrict__ ald, const int* __restrict__ off0,
    const int* __restrict__ csr0, const float* __restrict__ bias,
    unsigned short* __restrict__ Ahi,
    const float* __restrict__ Wfc, const float* __restrict__ bfc,
    const float* __restrict__ gamma, const float* __restrict__ beta,
    float* __restrict__ out) {
    int tid = threadIdx.x, lane = tid & 63, wid = tid >> 6;
    int dst = node_map(blockIdx.x, wid);
    int bbase = dst & ~511;          // batch * 512
    int dl = dst & 511;              // local node id
    int beg = off0[dl], end = off0[dl + 1], deg = end - beg;
    float ad0 = ald[2 * dst], ad1 = ald[2 * dst + 1];
    int col = lane * 8;
    float A[8] = {0.f, 0.f, 0.f, 0.f, 0.f, 0.f, 0.f, 0.f};

    if (deg <= 64) {
        float e0 = -1e30f, e1 = -1e30f;
        int sl = 0;
        if (lane < deg) {
            sl = csr0[beg + lane] + bbase;
            float a0 = als[2 * sl], a1 = als[2 * sl + 1];
            e0 = a0 + ad0; e0 = e0 > 0.f ? e0 : 0.2f * e0;
            e1 = a1 + ad1; e1 = e1 > 0.f ? e1 : 0.2f * e1;
        }
        float m0 = e0, m1 = e1;
#pragma unroll
        for (int m = 1; m < 64; m <<= 1) {
            m0 = fmaxf(m0, __shfl_xor(m0, m));
            m1 = fmaxf(m1, __shfl_xor(m1, m));
        }
        float x0 = (lane < deg) ? expf(e0 - m0) : 0.f;
        float x1 = (lane < deg) ? expf(e1 - m1) : 0.f;
        float d0 = x0, d1 = x1;
#pragma unroll
        for (int m = 1; m < 64; m <<= 1) {
            d0 += __shfl_xor(d0, m);
            d1 += __shfl_xor(d1, m);
        }
        float w0l = x0 / (d0 + 1e-16f);
        float w1l = x1 / (d1 + 1e-16f);
        // 1-deep software prefetch. ALL shuffles executed convergently
        // (deg is wave-uniform; no divergent branch wraps any __shfl).
        {
            int sv = __shfl(sl, 0);
            float wa = __shfl(w0l, 0), wb = __shfl(w1l, 0);
            float w = (lane < 32) ? wa : wb;
            uint4 hv = *(const uint4*)(Hin + (size_t)sv * HC_ + col);
            for (int e = 0; e < deg; ++e) {
                int en = (e + 1 < deg) ? e + 1 : 0;       // uniform clamp
                int sn = __shfl(sl, en);
                float wan = __shfl(w0l, en), wbn = __shfl(w1l, en);
                float wn = (lane < 32) ? wan : wbn;
                uint4 hn = *(const uint4*)(Hin + (size_t)sn * HC_ + col);
                float f0, f1;
                bf2x2(hv.x, f0, f1); A[0] = fmaf(w, f0, A[0]); A[1] = fmaf(w, f1, A[1]);
                bf2x2(hv.y, f0, f1); A[2] = fmaf(w, f0, A[2]); A[3] = fmaf(w, f1, A[3]);
                bf2x2(hv.z, f0, f1); A[4] = fmaf(w, f0, A[4]); A[5] = fmaf(w, f1, A[5]);
                bf2x2(hv.w, f0, f1); A[6] = fmaf(w, f0, A[6]); A[7] = fmaf(w, f1, A[7]);
                hv = hn; w = wn;
            }
        }
    } else {
        float m0 = -1e30f, m1 = -1e30f;
        for (int k = beg + lane; k < end; k += 64) {
            int s = csr0[k] + bbase;
            float e0 = als[2 * s] + ad0; e0 = e0 > 0.f ? e0 : 0.2f * e0;
            float e1 = als[2 * s + 1] + ad1; e1 = e1 > 0.f ? e1 : 0.2f * e1;
            m0 = fmaxf(m0, e0);
            m1 = fmaxf(m1, e1);
        }
#pragma unroll
        for (int m = 1; m < 64; m <<= 1) {
            m0 = fmaxf(m0, __shfl_xor(m0, m));
            m1 = fmaxf(m1, __shfl_xor(m1, m));
        }
        float d0 = 0.f, d1 = 0.f;
        for (int k = beg + lane; k < end; k += 64) {
            int s = csr0[k] + bbase;
            float e0 = als[2 * s] + ad0; e0 = e0 > 0.f ? e0 : 0.2f * e0;
            float e1 = als[2 * s + 1] + ad1; e1 = e1 > 0.f ? e1 : 0.2f * e1;
            d0 += expf(e0 - m0);
            d1 += expf(e1 - m1);
        }
#pragma unroll
        for (int m = 1; m < 64; m <<= 1) {
            d0 += __shfl_xor(d0, m);
            d1 += __shfl_xor(d1, m);
        }
        float inv0 = 1.f / (d0 + 1e-16f);
        float inv1 = 1.f / (d1 + 1e-16f);
        for (int k = beg; k < end; ++k) {
            int s = csr0[k] + bbase;
            float e0 = als[2 * s] + ad0; e0 = e0 > 0.f ? e0 : 0.2f * e0;
            float e1 = als[2 * s + 1] + ad1; e1 = e1 > 0.f ? e1 : 0.2f * e1;
            float w0 = expf(e0 - m0) * inv0;
            float w1 = expf(e1 - m1) * inv1;
            float w = (lane < 32) ? w0 : w1;
            uint4 hv = *(const uint4*)(Hin + (size_t)s * HC_ + col);
            float f0, f1;
            bf2x2(hv.x, f0, f1); A[0] = fmaf(w, f0, A[0]); A[1] = fmaf(w, f1, A[1]);
            bf2x2(hv.y, f0, f1); A[2] = fmaf(w, f0, A[2]); A[3] = fmaf(w, f1, A[3]);
            bf2x2(hv.z, f0, f1); A[4] = fmaf(w, f0, A[4]); A[5] = fmaf(w, f1, A[5]);
            bf2x2(hv.w, f0, f1); A[6] = fmaf(w, f0, A[6]); A[7] = fmaf(w, f1, A[7]);
        }
    }

#pragma unroll
    for (int j = 0; j < 8; ++j) A[j] += bias[col + j];

    if (MODE == 0) {
        uint4 uh;
        uh.x = pack2(f2bf(A[0]), f2bf(A[1]));
        uh.y = pack2(f2bf(A[2]), f2bf(A[3]));
        uh.z = pack2(f2bf(A[4]), f2bf(A[5]));
        uh.w = pack2(f2bf(A[6]), f2bf(A[7]));
        *(uint4*)&Ahi[(size_t)dst * HC_ + col] = uh;
    } else {
        float y = 0.f;
#pragma unroll
        for (int j = 0; j < 8; ++j) y = fmaf(A[j], Wfc[col + j], y);
#pragma unroll
        for (int m = 1; m < 64; m <<= 1) y += __shfl_xor(y, m);
        if (lane == 0) {
            y += bfc[0];
            y = y * (gamma[0] * rsqrtf(1.f + 1e-5f)) + beta[0];
            out[dst] = y > 0.f ? y : 0.f;
        }
    }
}

// ---------------- layer 2 GEMM: bf16x2 MFMA, 256x128 tile, bf16 out ---------
// + FUSED al2: partial dots with as2/ad2 from the LDS epilogue tile,
//   16-lane shuffle reduce, atomicAdd into als2/ald2 (zeroed by gemm1).
__global__ __launch_bounds__(512, 1) void gemm2_kernel(
    const unsigned short* __restrict__ Ahi,
    const unsigned short* __restrict__ Bhi, const unsigned short* __restrict__ Blo,
    unsigned short* __restrict__ H2,
    const float* __restrict__ as2, const float* __restrict__ ad2,
    float* __restrict__ als2, float* __restrict__ ald2) {
    __shared__ __align__(16) char smem[135168];
    const int tid = threadIdx.x, lane = tid & 63, wid = tid >> 6;
    const int wr = wid >> 1, wc = wid & 1;
    const int g = (blockIdx.x & 7) * 32 + (blockIdx.x >> 3);  // XCD swizzle
    const int row0 = (g >> 2) * 256, col0 = (g & 3) * 128;
    const int lr = lane & 15, lk = lane >> 4;
    const int x7 = lr & 7;

    f32x4 acc[4][4] = {};

    const char* gsrc[8];
    int loff[8];
#pragma unroll
    for (int l = 0; l < 8; ++l) {
        int i = tid + l * 512;
        if (i < 2048) {
            int r = i >> 3, c = i & 7;
            gsrc[l] = (const char*)(Ahi + (size_t)(row0 + r) * HC_ + ((c ^ (r & 7)) << 3));
            loff[l] = i << 4;
        } else if (i < 3072) {
            int j = i - 2048, r = j >> 3, c = j & 7;
            gsrc[l] = (const char*)(Bhi + (size_t)(col0 + r) * HC_ + ((c ^ (r & 7)) << 3));
            loff[l] = 32768 + (j << 4);
        } else {
            int j = i - 3072, r = j >> 3, c = j & 7;
            gsrc[l] = (const char*)(Blo + (size_t)(col0 + r) * HC_ + ((c ^ (r & 7)) << 3));
            loff[l] = 49152 + (j << 4);
        }
    }
    char* lds0 = smem;

#pragma unroll
    for (int l = 0; l < 8; ++l) async_cp16(gsrc[l], lds0 + loff[l]);
    asm volatile("s_waitcnt vmcnt(0)" ::: "memory");
    __builtin_amdgcn_s_barrier();

    int cur = 0;
    for (int kt = 0; kt < 8; ++kt) {
        if (kt < 7) {
            char* dst = lds0 + ((cur ^ 1) << 16);
#pragma unroll
            for (int l = 0; l < 8; ++l)
                async_cp16(gsrc[l] + (size_t)(kt + 1) * 128, dst + loff[l]);
        }
        const char* base = lds0 + (cur << 16);
#pragma unroll
        for (int kk = 0; kk < 2; ++kk) {
            bf16x8 a[4], bh[4], bl[4];
            int cx = ((kk * 4 + lk) ^ x7) << 4;
#pragma unroll
            for (int m = 0; m < 4; ++m) {
                int ra = wr * 64 + m * 16 + lr;
                int rb = wc * 64 + m * 16 + lr;
                a[m]  = *(const bf16x8*)(base + ra * 128 + cx);
                bh[m] = *(const bf16x8*)(base + 32768 + rb * 128 + cx);
                bl[m] = *(const bf16x8*)(base + 49152 + rb * 128 + cx);
            }
#pragma unroll
            for (int m = 0; m < 4; ++m)
#pragma unroll
                for (int n = 0; n < 4; ++n) {
                    acc[m][n] = __builtin_amdgcn_mfma_f32_16x16x32_bf16(a[m], bh[n], acc[m][n], 0, 0, 0);
                    acc[m][n] = __builtin_amdgcn_mfma_f32_16x16x32_bf16(a[m], bl[n], acc[m][n], 0, 0, 0);
                }
        }
        asm volatile("s_waitcnt vmcnt(0)" ::: "memory");
        __builtin_amdgcn_s_barrier();
        cur ^= 1;
    }

    // epilogue: acc -> LDS (padded) -> coalesced bf16 stores + fused al2
    float* tb = (float*)smem;
#pragma unroll
    for (int m = 0; m < 4; ++m)
#pragma unroll
        for (int i = 0; i < 4; ++i) {
            int row = wr * 64 + m * 16 + lk * 4 + i;
#pragma unroll
            for (int n = 0; n < 4; ++n)
                tb[row * 132 + wc * 64 + n * 16 + lr] = acc[m][n][i];
        }
    __syncthreads();
    const int head = col0 >> 8;                    // block's 128 cols lie in one head
    const float* a_s2 = as2 + head * C_ + (col0 & 255);
    const float* a_d2 = ad2 + head * C_ + (col0 & 255);
#pragma unroll
    for (int p = 0; p < 8; ++p) {
        int q = tid + p * 512;
        int row = q >> 4, cs = (q & 15) * 8;
        const float* v = &tb[row * 132 + cs];
        uint4 uh;
        uh.x = pack2(f2bf(v[0]), f2bf(v[1]));
        uh.y = pack2(f2bf(v[2]), f2bf(v[3]));
        uh.z = pack2(f2bf(v[4]), f2bf(v[5]));
        uh.w = pack2(f2bf(v[6]), f2bf(v[7]));
        *(uint4*)&H2[(size_t)(row0 + row) * HC_ + col0 + cs] = uh;
        float ps = 0.f, pd = 0.f;
#pragma unroll
        for (int j = 0; j < 8; ++j) {
            ps = fmaf(v[j], a_s2[cs + j], ps);
            pd = fmaf(v[j], a_d2[cs + j], pd);
        }
#pragma unroll
        for (int m = 1; m < 16; m <<= 1) {   // reduce across the 16 lanes of one row
            ps += __shfl_xor(ps, m);
            pd += __shfl_xor(pd, m);
        }
        if ((tid & 15) == 0) {
            atomicAdd(&als2[(row0 + row) * 2 + head], ps);
            atomicAdd(&ald2[(row0 + row) * 2 + head], pd);
        }
    }
}

// ---------------- launcher ----------------
extern "C" void kernel_launch(void* const* d_in, const int* in_sizes, int n_in,
                              void* d_out, int out_size, void* d_ws, size_t ws_size,
                              hipStream_t stream) {
    const float* data  = (const float*)d_in[0];
    const int*   eidx  = (const int*)d_in[1];
    const float* W1    = (const float*)d_in[2];
    const float* as1   = (const float*)d_in[3];
    const float* ad1   = (const float*)d_in[4];
    const float* b1    = (const float*)d_in[5];
    const float* W2    = (const float*)d_in[6];
    const float* as2   = (const float*)d_in[7];
    const float* ad2   = (const float*)d_in[8];
    const float* b2    = (const float*)d_in[9];
    const float* Wfc   = (const float*)d_in[10];
    const float* bfc   = (const float*)d_in[11];
    const float* gamma = (const float*)d_in[12];
    const float* beta  = (const float*)d_in[13];
    float* out = (float*)d_out;

    char* base = (char*)d_ws;
    size_t o = 0;
    auto take = [&](size_t bytes) {
        char* p = base + o;
        o = (o + bytes + 255) & ~(size_t)255;
        return p;
    };
    int*   off0 = (int*)take((size_t)(N_ + 1) * 4);
    int*   csr0 = (int*)take((size_t)EC_ * 4);
    float* als1 = (float*)take((size_t)T_ * 2 * 4);
    float* ald1 = (float*)take((size_t)T_ * 2 * 4);
    float* als2 = (float*)take((size_t)T_ * 2 * 4);
    float* ald2 = (float*)take((size_t)T_ * 2 * 4);
    unsigned short* hs1 = (unsigned short*)take((size_t)T_ * HC_ * 2);  // h1 bf16
    unsigned short* hs2 = (unsigned short*)take((size_t)T_ * HC_ * 2);  // h2 bf16
    unsigned short* Ahi = (unsigned short*)take((size_t)T_ * HC_ * 2);  // x1 bf16
    unsigned short* Bhi = (unsigned short*)take((size_t)HC_ * HC_ * 2);
    unsigned short* Blo = (unsigned short*)take((size_t)HC_ * HC_ * 2);

    gemm1_kernel<<<4353, 256, 0, stream>>>(data, W1, as1, ad1, hs1, als1, ald1,
                                           als2, ald2, eidx, W2, off0, csr0,
                                           Bhi, Blo);
    agg_kernel<0><<<4096, 256, 0, stream>>>(hs1, als1, ald1, off0, csr0, b1,
                                            Ahi, nullptr, nullptr, nullptr,
                                            nullptr, nullptr);
    gemm2_kernel<<<256, 512, 0, stream>>>(Ahi, Bhi, Blo, hs2, as2, ad2, als2, ald2);
    agg_kernel<1><<<4096, 256, 0, stream>>>(hs2, als2, ald2, off0, csr0, b2,
                                            nullptr, Wfc, bfc, gamma,
                                            beta, out);
}

// Round 10
// 92.392 us; speedup vs baseline: 1.1697x; 1.1697x over previous
//
#include <hip/hip_runtime.h>
#include <math.h>

#define B_  32
#define F_  10
#define N_  512
#define E_  8192
#define T_  16384      /* B_*N_ total nodes */
#define EC_ 8704       /* per-batch edges incl self-loops: E_+N_ */
#define HC_ 512
#define C_  256

typedef __attribute__((ext_vector_type(8))) short bf16x8;
typedef __attribute__((ext_vector_type(4))) float f32x4;

__device__ __forceinline__ unsigned short f2bf(float f) {
    unsigned int u = __float_as_uint(f);
    u = (u + 0x7fffu + ((u >> 16) & 1u)) >> 16;
    return (unsigned short)u;
}
__device__ __forceinline__ float bf2f(unsigned short b) {
    return __uint_as_float(((unsigned int)b) << 16);
}
__device__ __forceinline__ float dot4(f32x4 a, f32x4 b) {
    f32x4 m = a * b;
    return m[0] + m[1] + m[2] + m[3];
}
__device__ __forceinline__ unsigned int pack2(unsigned short a, unsigned short b) {
    return (unsigned int)a | ((unsigned int)b << 16);
}
// expand packed 2x bf16 -> 2 floats
__device__ __forceinline__ void bf2x2(unsigned int u, float& f0, float& f1) {
    f0 = __uint_as_float(u << 16);
    f1 = __uint_as_float(u & 0xffff0000u);
}
__device__ __forceinline__ void async_cp16(const void* g, void* l) {
    __builtin_amdgcn_global_load_lds(
        (const __attribute__((address_space(1))) unsigned int*)g,
        (__attribute__((address_space(3))) unsigned int*)l, 16, 0, 0);
}

// batch→XCD swizzle (4096-block kernels)
__device__ __forceinline__ int node_map(int bid, int wid) {
    int x = bid & 7;
    int rest = bid >> 3;          // 0..511
    int batch = x * 4 + (rest >> 7);
    int within = rest & 127;
    return batch * 512 + within * 4 + wid;
}

// ---------------- prep: W2 transpose+split (blocks 0..255) + per-batch CSR (block 256)
__global__ __launch_bounds__(1024) void prep_kernel(
    const int* __restrict__ eidx, const float* __restrict__ W2,
    int* __restrict__ off0, int* __restrict__ csr0,
    unsigned short* __restrict__ Bhi, unsigned short* __restrict__ Blo) {
    if (blockIdx.x < 256) {
        __shared__ float t[32][33];
        int bx = blockIdx.x & 15, by = blockIdx.x >> 4;
        int kb = bx * 32, nb = by * 32;
        int tx = threadIdx.x & 31, r = threadIdx.x >> 5;
        t[r][tx] = W2[(size_t)(kb + r) * HC_ + nb + tx];
        __syncthreads();
        float v = t[tx][r];
        unsigned short h = f2bf(v);
        Bhi[(size_t)(nb + r) * HC_ + kb + tx] = h;
        Blo[(size_t)(nb + r) * HC_ + kb + tx] = f2bf(v - bf2f(h));
    } else {
        // CSR for the batch-0 graph: 512 nodes, 8704 edges (8192 + self-loops)
        __shared__ int cnt[512];
        __shared__ int scn[512];
        int tid = threadIdx.x;
        if (tid < 512) cnt[tid] = 0;
        __syncthreads();
        const int* edst = eidx + E_;
        for (int j = tid; j < EC_; j += 1024) {
            int d = (j < E_) ? edst[j] : (j - E_);
            atomicAdd(&cnt[d], 1);
        }
        __syncthreads();
        if (tid < 512) scn[tid] = cnt[tid];
        __syncthreads();
        for (int dd = 1; dd < 512; dd <<= 1) {
            int add = (tid < 512 && tid >= dd) ? scn[tid - dd] : 0;
            __syncthreads();
            if (tid < 512) scn[tid] += add;
            __syncthreads();
        }
        if (tid < 512) {
            int excl = scn[tid] - cnt[tid];
            off0[tid] = excl;
            cnt[tid] = excl;            // cursor
        }
        if (tid == 0) off0[512] = EC_;
        __syncthreads();
        for (int j = tid; j < EC_; j += 1024) {
            int s, d;
            if (j < E_) { s = eidx[j]; d = edst[j]; }
            else { s = d = j - E_; }
            int pos = atomicAdd(&cnt[d], 1);
            csr0[pos] = s;
        }
    }
}

// ---------------- layer 1 GEMM (K=10): 8 nodes/wave, W1 hoisted to registers
// 512 blocks x 256 thr; wave stages 80 X floats in LDS, W1 slices live in VGPRs.
__global__ __launch_bounds__(256) void gemm1_kernel(
    const float* __restrict__ X, const float* __restrict__ W1,
    const float* __restrict__ a_s, const float* __restrict__ a_d,
    unsigned short* __restrict__ Hs, float* __restrict__ als,
    float* __restrict__ ald, float* __restrict__ als2z,
    float* __restrict__ ald2z) {
    __shared__ float xs[4][80];
    int tid = threadIdx.x, lane = tid & 63, w = tid >> 6;
    int q = blockIdx.x;                         // 0..511, XCD swizzle
    int batch = (q & 7) * 4 + (q >> 7);         // xcd*4 + hi
    int sub = (q >> 3) & 15;
    int nb = batch * 512 + sub * 32 + w * 8;    // this wave's 8 nodes
    int col = lane * 8;

    // hoist W1 row-slices + attention vectors (reused for all 8 nodes)
    f32x4 w1r[F_][2];
#pragma unroll
    for (int k = 0; k < F_; ++k) {
        w1r[k][0] = *(const f32x4*)&W1[k * HC_ + col];
        w1r[k][1] = *(const f32x4*)&W1[k * HC_ + col + 4];
    }
    f32x4 asl = *(const f32x4*)&a_s[col], ash = *(const f32x4*)&a_s[col + 4];
    f32x4 adl = *(const f32x4*)&a_d[col], adh = *(const f32x4*)&a_d[col + 4];

    // stage X for 8 nodes (80 floats) via coalesced loads
    const float* xp = X + (size_t)nb * F_;
    if (lane < 40) {
        xs[w][lane] = xp[lane];
        xs[w][lane + 40] = xp[lane + 40];
    }
    // zero layer-2 coeff accumulators (contiguous 16 floats per wave)
    if (lane < 16) als2z[nb * 2 + lane] = 0.f;
    else if (lane >= 48) ald2z[nb * 2 + lane - 48] = 0.f;

#pragma unroll
    for (int n = 0; n < 8; ++n) {
        f32x4 h0 = {0.f, 0.f, 0.f, 0.f}, h1 = h0;
#pragma unroll
        for (int k = 0; k < F_; ++k) {
            float xv = xs[w][n * F_ + k];       // LDS broadcast
            h0 += xv * w1r[k][0];
            h1 += xv * w1r[k][1];
        }
        int node = nb + n;
        uint4 uh;
        uh.x = pack2(f2bf(h0[0]), f2bf(h0[1]));
        uh.y = pack2(f2bf(h0[2]), f2bf(h0[3]));
        uh.z = pack2(f2bf(h1[0]), f2bf(h1[1]));
        uh.w = pack2(f2bf(h1[2]), f2bf(h1[3]));
        *(uint4*)&Hs[(size_t)node * HC_ + col] = uh;
        float ps = dot4(h0, asl) + dot4(h1, ash);
        float pd = dot4(h0, adl) + dot4(h1, adh);
#pragma unroll
        for (int m = 1; m <= 16; m <<= 1) {
            ps += __shfl_xor(ps, m);
            pd += __shfl_xor(pd, m);
        }
        if (lane == 0)  { als[node * 2 + 0] = ps; ald[node * 2 + 0] = pd; }
        if (lane == 32) { als[node * 2 + 1] = ps; ald[node * 2 + 1] = pd; }
    }
}

// ---------------- GAT aggregation: wave per dst, per-batch CSR --------------
// MODE 0: output bf16 x1 (feeds MFMA gemm2). MODE 1: fused FC+BN+ReLU.
template <int MODE>
__global__ __launch_bounds__(256) void agg_kernel(
    const unsigned short* __restrict__ Hin, const float* __restrict__ als,
    const float* __restrict__ ald, const int* __restrict__ off0,
    const int* __restrict__ csr0, const float* __restrict__ bias,
    unsigned short* __restrict__ Ahi,
    const float* __restrict__ Wfc, const float* __restrict__ bfc,
    const float* __restrict__ gamma, const float* __restrict__ beta,
    float* __restrict__ out) {
    int tid = threadIdx.x, lane = tid & 63, wid = tid >> 6;
    int dst = node_map(blockIdx.x, wid);
    int bbase = dst & ~511;          // batch * 512
    int dl = dst & 511;              // local node id
    int beg = off0[dl], end = off0[dl + 1], deg = end - beg;
    float ad0 = ald[2 * dst], ad1 = ald[2 * dst + 1];
    int col = lane * 8;
    float A[8] = {0.f, 0.f, 0.f, 0.f, 0.f, 0.f, 0.f, 0.f};

    if (deg <= 64) {
        float e0 = -1e30f, e1 = -1e30f;
        int sl = 0;
        if (lane < deg) {
            sl = csr0[beg + lane] + bbase;
            float a0 = als[2 * sl], a1 = als[2 * sl + 1];
            e0 = a0 + ad0; e0 = e0 > 0.f ? e0 : 0.2f * e0;
            e1 = a1 + ad1; e1 = e1 > 0.f ? e1 : 0.2f * e1;
        }
        float m0 = e0, m1 = e1;
#pragma unroll
        for (int m = 1; m < 64; m <<= 1) {
            m0 = fmaxf(m0, __shfl_xor(m0, m));
            m1 = fmaxf(m1, __shfl_xor(m1, m));
        }
        float x0 = (lane < deg) ? expf(e0 - m0) : 0.f;
        float x1 = (lane < deg) ? expf(e1 - m1) : 0.f;
        float d0 = x0, d1 = x1;
#pragma unroll
        for (int m = 1; m < 64; m <<= 1) {
            d0 += __shfl_xor(d0, m);
            d1 += __shfl_xor(d1, m);
        }
        float w0l = x0 / (d0 + 1e-16f);
        float w1l = x1 / (d1 + 1e-16f);
        for (int e = 0; e < deg; ++e) {
            int s = __shfl(sl, e);
            // CONVERGENT shuffles (ternary around __shfl is UB under divergence)
            float wa = __shfl(w0l, e);
            float wb = __shfl(w1l, e);
            float w = (lane < 32) ? wa : wb;
            uint4 hv = *(const uint4*)(Hin + (size_t)s * HC_ + col);
            float f0, f1;
            bf2x2(hv.x, f0, f1); A[0] = fmaf(w, f0, A[0]); A[1] = fmaf(w, f1, A[1]);
            bf2x2(hv.y, f0, f1); A[2] = fmaf(w, f0, A[2]); A[3] = fmaf(w, f1, A[3]);
            bf2x2(hv.z, f0, f1); A[4] = fmaf(w, f0, A[4]); A[5] = fmaf(w, f1, A[5]);
            bf2x2(hv.w, f0, f1); A[6] = fmaf(w, f0, A[6]); A[7] = fmaf(w, f1, A[7]);
        }
    } else {
        float m0 = -1e30f, m1 = -1e30f;
        for (int k = beg + lane; k < end; k += 64) {
            int s = csr0[k] + bbase;
            float e0 = als[2 * s] + ad0; e0 = e0 > 0.f ? e0 : 0.2f * e0;
            float e1 = als[2 * s + 1] + ad1; e1 = e1 > 0.f ? e1 : 0.2f * e1;
            m0 = fmaxf(m0, e0);
            m1 = fmaxf(m1, e1);
        }
#pragma unroll
        for (int m = 1; m < 64; m <<= 1) {
            m0 = fmaxf(m0, __shfl_xor(m0, m));
            m1 = fmaxf(m1, __shfl_xor(m1, m));
        }
        float d0 = 0.f, d1 = 0.f;
        for (int k = beg + lane; k < end; k += 64) {
            int s = csr0[k] + bbase;
            float e0 = als[2 * s] + ad0; e0 = e0 > 0.f ? e0 : 0.2f * e0;
            float e1 = als[2 * s + 1] + ad1; e1 = e1 > 0.f ? e1 : 0.2f * e1;
            d0 += expf(e0 - m0);
            d1 += expf(e1 - m1);
        }
#pragma unroll
        for (int m = 1; m < 64; m <<= 1) {
            d0 += __shfl_xor(d0, m);
            d1 += __shfl_xor(d1, m);
        }
        float inv0 = 1.f / (d0 + 1e-16f);
        float inv1 = 1.f / (d1 + 1e-16f);
        for (int k = beg; k < end; ++k) {
            int s = csr0[k] + bbase;
            float e0 = als[2 * s] + ad0; e0 = e0 > 0.f ? e0 : 0.2f * e0;
            float e1 = als[2 * s + 1] + ad1; e1 = e1 > 0.f ? e1 : 0.2f * e1;
            float w0 = expf(e0 - m0) * inv0;
            float w1 = expf(e1 - m1) * inv1;
            float w = (lane < 32) ? w0 : w1;
            uint4 hv = *(const uint4*)(Hin + (size_t)s * HC_ + col);
            float f0, f1;
            bf2x2(hv.x, f0, f1); A[0] = fmaf(w, f0, A[0]); A[1] = fmaf(w, f1, A[1]);
            bf2x2(hv.y, f0, f1); A[2] = fmaf(w, f0, A[2]); A[3] = fmaf(w, f1, A[3]);
            bf2x2(hv.z, f0, f1); A[4] = fmaf(w, f0, A[4]); A[5] = fmaf(w, f1, A[5]);
            bf2x2(hv.w, f0, f1); A[6] = fmaf(w, f0, A[6]); A[7] = fmaf(w, f1, A[7]);
        }
    }

#pragma unroll
    for (int j = 0; j < 8; ++j) A[j] += bias[col + j];

    if (MODE == 0) {
        uint4 uh;
        uh.x = pack2(f2bf(A[0]), f2bf(A[1]));
        uh.y = pack2(f2bf(A[2]), f2bf(A[3]));
        uh.z = pack2(f2bf(A[4]), f2bf(A[5]));
        uh.w = pack2(f2bf(A[6]), f2bf(A[7]));
        *(uint4*)&Ahi[(size_t)dst * HC_ + col] = uh;
    } else {
        float y = 0.f;
#pragma unroll
        for (int j = 0; j < 8; ++j) y = fmaf(A[j], Wfc[col + j], y);
#pragma unroll
        for (int m = 1; m < 64; m <<= 1) y += __shfl_xor(y, m);
        if (lane == 0) {
            y += bfc[0];
            y = y * (gamma[0] * rsqrtf(1.f + 1e-5f)) + beta[0];
            out[dst] = y > 0.f ? y : 0.f;
        }
    }
}

// ---------------- layer 2 GEMM: bf16x2 MFMA, 256x128 tile, bf16 out ---------
// + FUSED al2: partial dots with as2/ad2 from the LDS epilogue tile,
//   16-lane shuffle reduce, atomicAdd into als2/ald2 (zeroed by gemm1).
__global__ __launch_bounds__(512, 1) void gemm2_kernel(
    const unsigned short* __restrict__ Ahi,
    const unsigned short* __restrict__ Bhi, const unsigned short* __restrict__ Blo,
    unsigned short* __restrict__ H2,
    const float* __restrict__ as2, const float* __restrict__ ad2,
    float* __restrict__ als2, float* __restrict__ ald2) {
    __shared__ __align__(16) char smem[135168];
    const int tid = threadIdx.x, lane = tid & 63, wid = tid >> 6;
    const int wr = wid >> 1, wc = wid & 1;
    const int g = (blockIdx.x & 7) * 32 + (blockIdx.x >> 3);  // XCD swizzle
    const int row0 = (g >> 2) * 256, col0 = (g & 3) * 128;
    const int lr = lane & 15, lk = lane >> 4;
    const int x7 = lr & 7;

    f32x4 acc[4][4] = {};

    const char* gsrc[8];
    int loff[8];
#pragma unroll
    for (int l = 0; l < 8; ++l) {
        int i = tid + l * 512;
        if (i < 2048) {
            int r = i >> 3, c = i & 7;
            gsrc[l] = (const char*)(Ahi + (size_t)(row0 + r) * HC_ + ((c ^ (r & 7)) << 3));
            loff[l] = i << 4;
        } else if (i < 3072) {
            int j = i - 2048, r = j >> 3, c = j & 7;
            gsrc[l] = (const char*)(Bhi + (size_t)(col0 + r) * HC_ + ((c ^ (r & 7)) << 3));
            loff[l] = 32768 + (j << 4);
        } else {
            int j = i - 3072, r = j >> 3, c = j & 7;
            gsrc[l] = (const char*)(Blo + (size_t)(col0 + r) * HC_ + ((c ^ (r & 7)) << 3));
            loff[l] = 49152 + (j << 4);
        }
    }
    char* lds0 = smem;

#pragma unroll
    for (int l = 0; l < 8; ++l) async_cp16(gsrc[l], lds0 + loff[l]);
    asm volatile("s_waitcnt vmcnt(0)" ::: "memory");
    __builtin_amdgcn_s_barrier();

    int cur = 0;
    for (int kt = 0; kt < 8; ++kt) {
        if (kt < 7) {
            char* dst = lds0 + ((cur ^ 1) << 16);
#pragma unroll
            for (int l = 0; l < 8; ++l)
                async_cp16(gsrc[l] + (size_t)(kt + 1) * 128, dst + loff[l]);
        }
        const char* base = lds0 + (cur << 16);
#pragma unroll
        for (int kk = 0; kk < 2; ++kk) {
            bf16x8 a[4], bh[4], bl[4];
            int cx = ((kk * 4 + lk) ^ x7) << 4;
#pragma unroll
            for (int m = 0; m < 4; ++m) {
                int ra = wr * 64 + m * 16 + lr;
                int rb = wc * 64 + m * 16 + lr;
                a[m]  = *(const bf16x8*)(base + ra * 128 + cx);
                bh[m] = *(const bf16x8*)(base + 32768 + rb * 128 + cx);
                bl[m] = *(const bf16x8*)(base + 49152 + rb * 128 + cx);
            }
#pragma unroll
            for (int m = 0; m < 4; ++m)
#pragma unroll
                for (int n = 0; n < 4; ++n) {
                    acc[m][n] = __builtin_amdgcn_mfma_f32_16x16x32_bf16(a[m], bh[n], acc[m][n], 0, 0, 0);
                    acc[m][n] = __builtin_amdgcn_mfma_f32_16x16x32_bf16(a[m], bl[n], acc[m][n], 0, 0, 0);
                }
        }
        asm volatile("s_waitcnt vmcnt(0)" ::: "memory");
        __builtin_amdgcn_s_barrier();
        cur ^= 1;
    }

    // epilogue: acc -> LDS (padded) -> coalesced bf16 stores + fused al2
    float* tb = (float*)smem;
#pragma unroll
    for (int m = 0; m < 4; ++m)
#pragma unroll
        for (int i = 0; i < 4; ++i) {
            int row = wr * 64 + m * 16 + lk * 4 + i;
#pragma unroll
            for (int n = 0; n < 4; ++n)
                tb[row * 132 + wc * 64 + n * 16 + lr] = acc[m][n][i];
        }
    __syncthreads();
    const int head = col0 >> 8;                    // block's 128 cols lie in one head
    const float* a_s2 = as2 + head * C_ + (col0 & 255);
    const float* a_d2 = ad2 + head * C_ + (col0 & 255);
#pragma unroll
    for (int p = 0; p < 8; ++p) {
        int q = tid + p * 512;
        int row = q >> 4, cs = (q & 15) * 8;
        const float* v = &tb[row * 132 + cs];
        uint4 uh;
        uh.x = pack2(f2bf(v[0]), f2bf(v[1]));
        uh.y = pack2(f2bf(v[2]), f2bf(v[3]));
        uh.z = pack2(f2bf(v[4]), f2bf(v[5]));
        uh.w = pack2(f2bf(v[6]), f2bf(v[7]));
        *(uint4*)&H2[(size_t)(row0 + row) * HC_ + col0 + cs] = uh;
        float ps = 0.f, pd = 0.f;
#pragma unroll
        for (int j = 0; j < 8; ++j) {
            ps = fmaf(v[j], a_s2[cs + j], ps);
            pd = fmaf(v[j], a_d2[cs + j], pd);
        }
#pragma unroll
        for (int m = 1; m < 16; m <<= 1) {   // reduce across the 16 lanes of one row
            ps += __shfl_xor(ps, m);
            pd += __shfl_xor(pd, m);
        }
        if ((tid & 15) == 0) {
            atomicAdd(&als2[(row0 + row) * 2 + head], ps);
            atomicAdd(&ald2[(row0 + row) * 2 + head], pd);
        }
    }
}

// ---------------- launcher ----------------
extern "C" void kernel_launch(void* const* d_in, const int* in_sizes, int n_in,
                              void* d_out, int out_size, void* d_ws, size_t ws_size,
                              hipStream_t stream) {
    const float* data  = (const float*)d_in[0];
    const int*   eidx  = (const int*)d_in[1];
    const float* W1    = (const float*)d_in[2];
    const float* as1   = (const float*)d_in[3];
    const float* ad1   = (const float*)d_in[4];
    const float* b1    = (const float*)d_in[5];
    const float* W2    = (const float*)d_in[6];
    const float* as2   = (const float*)d_in[7];
    const float* ad2   = (const float*)d_in[8];
    const float* b2    = (const float*)d_in[9];
    const float* Wfc   = (const float*)d_in[10];
    const float* bfc   = (const float*)d_in[11];
    const float* gamma = (const float*)d_in[12];
    const float* beta  = (const float*)d_in[13];
    float* out = (float*)d_out;

    char* base = (char*)d_ws;
    size_t o = 0;
    auto take = [&](size_t bytes) {
        char* p = base + o;
        o = (o + bytes + 255) & ~(size_t)255;
        return p;
    };
    int*   off0 = (int*)take((size_t)(N_ + 1) * 4);
    int*   csr0 = (int*)take((size_t)EC_ * 4);
    float* als1 = (float*)take((size_t)T_ * 2 * 4);
    float* ald1 = (float*)take((size_t)T_ * 2 * 4);
    float* als2 = (float*)take((size_t)T_ * 2 * 4);
    float* ald2 = (float*)take((size_t)T_ * 2 * 4);
    unsigned short* hs1 = (unsigned short*)take((size_t)T_ * HC_ * 2);  // h1 bf16
    unsigned short* hs2 = (unsigned short*)take((size_t)T_ * HC_ * 2);  // h2 bf16
    unsigned short* Ahi = (unsigned short*)take((size_t)T_ * HC_ * 2);  // x1 bf16
    unsigned short* Bhi = (unsigned short*)take((size_t)HC_ * HC_ * 2);
    unsigned short* Blo = (unsigned short*)take((size_t)HC_ * HC_ * 2);

    prep_kernel<<<257, 1024, 0, stream>>>(eidx, W2, off0, csr0, Bhi, Blo);
    gemm1_kernel<<<512, 256, 0, stream>>>(data, W1, as1, ad1, hs1, als1, ald1,
                                          als2, ald2);
    agg_kernel<0><<<4096, 256, 0, stream>>>(hs1, als1, ald1, off0, csr0, b1,
                                            Ahi, nullptr, nullptr, nullptr,
                                            nullptr, nullptr);
    gemm2_kernel<<<256, 512, 0, stream>>>(Ahi, Bhi, Blo, hs2, as2, ad2, als2, ald2);
    agg_kernel<1><<<4096, 256, 0, stream>>>(hs2, als2, ald2, off0, csr0, b2,
                                            nullptr, Wfc, bfc, gamma,
                                            beta, out);
}